// Round 2
// baseline (71.007 us; speedup 1.0000x reference)
//
#include <hip/hip_runtime.h>

#define QSIZE     100000   // NUM_CLASSES * NUM_INSTANCE
#define FEAT      256
#define NPROP     1024
#define ROW_F4    (FEAT / 4)   // 64

// ---------------------------------------------------------------------------
// Kernel 1: sorted-unique of n (<=1024) int32 labels, one block.
// For each element, is_first = no earlier equal element.
// For first occurrences, pos = #(first j with value < mine)  -> sorted order.
// Writes uniq values (as float) to ws and the unique count U.
// ---------------------------------------------------------------------------
__global__ __launch_bounds__(NPROP)
void unique_kernel(const int* __restrict__ labels, int n,
                   float* __restrict__ uniq_ws, int* __restrict__ U_ws) {
    __shared__ int s[NPROP];
    __shared__ int first[NPROP];
    __shared__ int cnt;
    const int tid = threadIdx.x;
    if (tid == 0) cnt = 0;
    // sentinel larger than any valid label so it can never be a "first" min
    s[tid] = (tid < n) ? labels[tid] : 0x7fffffff;
    __syncthreads();

    const int L = s[tid];
    int dup = 0;
    for (int j = 0; j < tid; ++j) dup += (s[j] == L);
    const int isf = (tid < n) && (dup == 0);
    first[tid] = isf;
    __syncthreads();

    if (isf) {
        int pos = 0;
        for (int j = 0; j < NPROP; ++j) pos += (first[j] & (s[j] < L));
        uniq_ws[pos] = (float)L;
        atomicAdd(&cnt, 1);
    }
    __syncthreads();
    if (tid == 0) *U_ws = cnt;
}

// ---------------------------------------------------------------------------
// Kernel 2: assemble outputs.
//   out0 (QSIZE x FEAT): rows [0,U) <- features rows, else queue_in rows
//   out1 (QSIZE):        [0,U) <- uniq values,       else qlabel_in
// float4-vectorized grid-stride; writes every output element each call.
// ---------------------------------------------------------------------------
__global__ __launch_bounds__(256)
void assemble_kernel(const float4* __restrict__ feat4,
                     const float4* __restrict__ qin4,
                     const float*  __restrict__ qlab_in,
                     const float*  __restrict__ uniq_ws,
                     const int*    __restrict__ U_ws,
                     float4* __restrict__ out0,
                     float*  __restrict__ out1) {
    const int U = *U_ws;
    const long total4 = (long)QSIZE * ROW_F4;          // 6,400,000 float4
    const long stride = (long)gridDim.x * blockDim.x;
    const long g0 = (long)blockIdx.x * blockDim.x + threadIdx.x;

    for (long i = g0; i < total4; i += stride) {
        const int row = (int)(i >> 6);                  // ROW_F4 == 64
        out0[i] = (row < U) ? feat4[i] : qin4[i];       // feat idx == i since row<U<=1024
    }
    for (long i = g0; i < QSIZE; i += stride) {
        out1[i] = (i < (long)U) ? uniq_ws[i] : qlab_in[i];
    }
}

extern "C" void kernel_launch(void* const* d_in, const int* in_sizes, int n_in,
                              void* d_out, int out_size, void* d_ws, size_t ws_size,
                              hipStream_t stream) {
    const float* features  = (const float*)d_in[0];   // (1024, 256) f32
    const int*   pid_labels = (const int*)d_in[1];    // (1024,) int32
    const float* queue_in  = (const float*)d_in[2];   // (100000, 256) f32
    const float* qlabel_in = (const float*)d_in[3];   // (100000,) f32
    const int n = in_sizes[1];

    float* out0 = (float*)d_out;                      // queue output
    float* out1 = out0 + (size_t)QSIZE * FEAT;        // qlabel output

    float* uniq_ws = (float*)d_ws;                    // 1024 floats
    int*   U_ws    = (int*)((char*)d_ws + NPROP * sizeof(float));

    unique_kernel<<<1, NPROP, 0, stream>>>(pid_labels, n, uniq_ws, U_ws);
    assemble_kernel<<<2048, 256, 0, stream>>>(
        (const float4*)features, (const float4*)queue_in, qlabel_in,
        uniq_ws, U_ws, (float4*)out0, out1);
}

// Round 5
// 35.071 us; speedup vs baseline: 2.0247x; 2.0247x over previous
//
#include <hip/hip_runtime.h>

#define QSIZE    100000   // NUM_CLASSES * NUM_INSTANCE
#define FEAT     256
#define NPROP    1024
#define NCLASS   50000
#define NWORDS   1563     // ceil(NCLASS/32)

#define NB_MAIN  6250     // 6,400,000 float4 / 1024 per block
#define NB_FIX   64       // 65,536 float4 (= out0 rows [0,1024)) / 1024 per block
#define NB_LAB   98       // ceil(100000/1024)

typedef float fvec4 __attribute__((ext_vector_type(4)));

// ---------------------------------------------------------------------------
// Kernel 1: sorted-unique of n (<=1024) labels in [0, NCLASS) via LDS bitmap.
// Bitmap mark -> per-thread popcount of 2 owned words -> block scan -> emit
// set bits in ascending order. Writes uniq (as float) + U.
// ---------------------------------------------------------------------------
__global__ __launch_bounds__(1024)
void unique_kernel(const int* __restrict__ labels, int n,
                   float* __restrict__ uniq_ws, int* __restrict__ U_ws) {
    __shared__ unsigned bm[NWORDS];
    __shared__ int wsum[16];
    __shared__ int wbase[16];
    const int tid = threadIdx.x;

    for (int w = tid; w < NWORDS; w += 1024) bm[w] = 0u;
    __syncthreads();

    if (tid < n) {
        const int L = labels[tid];
        atomicOr(&bm[L >> 5], 1u << (L & 31));
    }
    __syncthreads();

    // each thread owns words [2*tid, 2*tid+2)
    const int b0 = 2 * tid;
    unsigned w0 = 0u, w1 = 0u;
    int c = 0;
    if (b0 < NWORDS)     { w0 = bm[b0];     c += __popc(w0); }
    if (b0 + 1 < NWORDS) { w1 = bm[b0 + 1]; c += __popc(w1); }

    // inclusive scan within each 64-lane wave
    const int lane = tid & 63, wave = tid >> 6;
    int sc = c;
    for (int off = 1; off < 64; off <<= 1) {
        int o = __shfl_up(sc, off, 64);
        if (lane >= off) sc += o;
    }
    if (lane == 63) wsum[wave] = sc;
    __syncthreads();

    if (tid == 0) {
        int acc = 0;
        for (int i = 0; i < 16; ++i) { wbase[i] = acc; acc += wsum[i]; }
        *U_ws = acc;
    }
    __syncthreads();

    int pos = wbase[wave] + (sc - c);   // exclusive prefix for this thread
    while (w0) {
        int b = __ffs(w0) - 1; w0 &= w0 - 1;
        uniq_ws[pos++] = (float)(b0 * 32 + b);
    }
    while (w1) {
        int b = __ffs(w1) - 1; w1 &= w1 - 1;
        uniq_ws[pos++] = (float)((b0 + 1) * 32 + b);
    }
}

// ---------------------------------------------------------------------------
// Kernel 2: assemble outputs. Fixed assignment, 4 fvec4 per thread, block
// role by blockIdx (wave-uniform), non-temporal stores (output never re-read,
// keep the input L3-resident across replays).
//   blocks [0, NB_MAIN):          out0; first NB_FIX blocks are U-dependent
//   blocks [NB_MAIN, +NB_LAB):    out1 labels
// ---------------------------------------------------------------------------
__global__ __launch_bounds__(256)
void assemble_kernel(const fvec4* __restrict__ feat4,
                     const fvec4* __restrict__ qin4,
                     const float* __restrict__ qlab_in,
                     const float* __restrict__ uniq_ws,
                     const int*   __restrict__ U_ws,
                     fvec4* __restrict__ out0,
                     float* __restrict__ out1) {
    const int b = blockIdx.x;
    const int tid = threadIdx.x;

    if (b < NB_MAIN) {
        const int base = b * 1024 + tid;
        if (b < NB_FIX) {
            // f4 indices [0, 65536) = rows [0, 1024): select by row<U
            const int U = *U_ws;
            #pragma unroll
            for (int k = 0; k < 4; ++k) {
                const int i = base + k * 256;
                const int row = i >> 6;              // ROW_F4 == 64
                const fvec4 f = feat4[i];            // i < 65536, safe
                const fvec4 q = qin4[i];
                __builtin_nontemporal_store(row < U ? f : q, &out0[i]);
            }
        } else {
            // rows >= 1024 >= U: pure copy
            fvec4 v0 = qin4[base];
            fvec4 v1 = qin4[base + 256];
            fvec4 v2 = qin4[base + 512];
            fvec4 v3 = qin4[base + 768];
            __builtin_nontemporal_store(v0, &out0[base]);
            __builtin_nontemporal_store(v1, &out0[base + 256]);
            __builtin_nontemporal_store(v2, &out0[base + 512]);
            __builtin_nontemporal_store(v3, &out0[base + 768]);
        }
    } else {
        const int b2 = b - NB_MAIN;
        const int base = b2 * 1024 + tid;
        if (b2 == 0) {
            // j in [0, 1024): select uniq vs qlabel by j<U (both loads safe)
            const int U = *U_ws;
            #pragma unroll
            for (int k = 0; k < 4; ++k) {
                const int j = base + k * 256;
                const float u = uniq_ws[j];
                const float q = qlab_in[j];
                __builtin_nontemporal_store(j < U ? u : q, &out1[j]);
            }
        } else {
            #pragma unroll
            for (int k = 0; k < 4; ++k) {
                const int j = base + k * 256;
                if (j < QSIZE)
                    __builtin_nontemporal_store(qlab_in[j], &out1[j]);
            }
        }
    }
}

extern "C" void kernel_launch(void* const* d_in, const int* in_sizes, int n_in,
                              void* d_out, int out_size, void* d_ws, size_t ws_size,
                              hipStream_t stream) {
    const float* features   = (const float*)d_in[0];  // (1024, 256) f32
    const int*   pid_labels = (const int*)d_in[1];    // (1024,) int32
    const float* queue_in   = (const float*)d_in[2];  // (100000, 256) f32
    const float* qlabel_in  = (const float*)d_in[3];  // (100000,) f32
    const int n = in_sizes[1];

    float* out0 = (float*)d_out;                      // queue output
    float* out1 = out0 + (size_t)QSIZE * FEAT;        // qlabel output

    float* uniq_ws = (float*)d_ws;                    // 1024 floats
    int*   U_ws    = (int*)((char*)d_ws + NPROP * sizeof(float));

    unique_kernel<<<1, NPROP, 0, stream>>>(pid_labels, n, uniq_ws, U_ws);
    assemble_kernel<<<NB_MAIN + NB_LAB, 256, 0, stream>>>(
        (const fvec4*)features, (const fvec4*)queue_in, qlabel_in,
        uniq_ws, U_ws, (fvec4*)out0, out1);
}

// Round 6
// 30.135 us; speedup vs baseline: 2.3563x; 1.1638x over previous
//
#include <hip/hip_runtime.h>

#define QSIZE    100000   // NUM_CLASSES * NUM_INSTANCE
#define NPROP    1024
#define NCLASS   50000
#define NWORDS   1563     // ceil(NCLASS/32)
#define WPT      7        // bitmap words per thread (256 thr): 256*7 = 1792 >= 1563

#define NB_MAIN  6250     // 6,400,000 float4 / 1024 per block (out0)
#define NB_FIX   64       // 65,536 float4 (= out0 rows [0,1024)) / 1024 per block
#define NB_LAB   98       // ceil(100000/1024) (out1)

typedef float fvec4 __attribute__((ext_vector_type(4)));

// ---------------------------------------------------------------------------
// Single fused kernel. Block roles by blockIdx (wave-uniform):
//   b in [0, NB_FIX):        out0 rows [0,1024) — needs U only; computes U
//                            redundantly via LDS bitmap popcount (overlapped
//                            with the copy blocks that saturate HBM).
//   b in [NB_FIX, NB_MAIN):  pure out0 copy (rows >= 1024 >= U).
//   b == NB_MAIN:            out1[0..1024) — computes full sorted unique in
//                            LDS (bitmap + scan + ordered emit).
//   b >  NB_MAIN:            out1 copy with tail guard.
// All output stores non-temporal (output never re-read; keep inputs cached).
// No cross-block communication -> no dispatch-order assumptions.
// ---------------------------------------------------------------------------
__global__ __launch_bounds__(256)
void fused_kernel(const fvec4* __restrict__ feat4,
                  const fvec4* __restrict__ qin4,
                  const float* __restrict__ qlab_in,
                  const int*   __restrict__ labels,
                  int n,
                  fvec4* __restrict__ out0,
                  float* __restrict__ out1) {
    __shared__ unsigned bm[NWORDS];
    __shared__ float lds_u[NPROP];
    __shared__ int wsum[4];
    __shared__ int Ush;

    const int b   = blockIdx.x;
    const int tid = threadIdx.x;

    if (b < NB_MAIN) {
        const int base = b * 1024 + tid;
        if (b < NB_FIX) {
            // Issue all 8 global loads first (hide under bitmap work).
            fvec4 f[4], q[4];
            #pragma unroll
            for (int k = 0; k < 4; ++k) {
                f[k] = feat4[base + k * 256];   // i < 65536, safe
                q[k] = qin4[base + k * 256];
            }
            // U = number of distinct labels (bitmap popcount).
            for (int w = tid; w < NWORDS; w += 256) bm[w] = 0u;
            if (tid == 0) Ush = 0;
            __syncthreads();
            for (int j = tid; j < n; j += 256) {
                const int L = labels[j];
                atomicOr(&bm[L >> 5], 1u << (L & 31));
            }
            __syncthreads();
            int c = 0;
            for (int w = tid; w < NWORDS; w += 256) c += __popc(bm[w]);
            #pragma unroll
            for (int off = 32; off; off >>= 1) c += __shfl_down(c, off, 64);
            if ((tid & 63) == 0) atomicAdd(&Ush, c);
            __syncthreads();
            const int U = Ush;
            #pragma unroll
            for (int k = 0; k < 4; ++k) {
                const int i = base + k * 256;
                const int row = i >> 6;          // ROW_F4 == 64
                __builtin_nontemporal_store(row < U ? f[k] : q[k], &out0[i]);
            }
        } else {
            // rows >= 1024 >= U: pure copy, 4-deep ILP
            fvec4 v0 = qin4[base];
            fvec4 v1 = qin4[base + 256];
            fvec4 v2 = qin4[base + 512];
            fvec4 v3 = qin4[base + 768];
            __builtin_nontemporal_store(v0, &out0[base]);
            __builtin_nontemporal_store(v1, &out0[base + 256]);
            __builtin_nontemporal_store(v2, &out0[base + 512]);
            __builtin_nontemporal_store(v3, &out0[base + 768]);
        }
    } else {
        const int b2 = b - NB_MAIN;
        if (b2 == 0) {
            // Full sorted unique into lds_u[0..U), then select-write out1[0..1024).
            for (int w = tid; w < NWORDS; w += 256) bm[w] = 0u;
            __syncthreads();
            for (int j = tid; j < n; j += 256) {
                const int L = labels[j];
                atomicOr(&bm[L >> 5], 1u << (L & 31));
            }
            __syncthreads();
            // contiguous word ownership for ordered emission
            const int w0   = tid * WPT;
            const int wend = (w0 + WPT < NWORDS) ? (w0 + WPT) : NWORDS;
            int c = 0;
            for (int w = w0; w < wend; ++w) c += __popc(bm[w]);
            // inclusive wave scan, then cross-wave bases
            const int lane = tid & 63, wv = tid >> 6;
            int sc = c;
            for (int off = 1; off < 64; off <<= 1) {
                const int o = __shfl_up(sc, off, 64);
                if (lane >= off) sc += o;
            }
            if (lane == 63) wsum[wv] = sc;
            __syncthreads();
            int wb = 0;
            for (int i = 0; i < wv; ++i) wb += wsum[i];
            const int U = wsum[0] + wsum[1] + wsum[2] + wsum[3];
            int pos = wb + (sc - c);             // exclusive prefix
            for (int w = w0; w < wend; ++w) {
                unsigned bits = bm[w];
                while (bits) {
                    const int bb = __ffs(bits) - 1; bits &= bits - 1;
                    lds_u[pos++] = (float)(w * 32 + bb);
                }
            }
            __syncthreads();
            #pragma unroll
            for (int k = 0; k < 4; ++k) {
                const int j = tid + k * 256;     // j in [0,1024)
                const float u = lds_u[j];        // junk for j>=U, selected away
                const float ql = qlab_in[j];
                __builtin_nontemporal_store(j < U ? u : ql, &out1[j]);
            }
        } else {
            const int basej = b2 * 1024 + tid;
            #pragma unroll
            for (int k = 0; k < 4; ++k) {
                const int j = basej + k * 256;
                if (j < QSIZE)
                    __builtin_nontemporal_store(qlab_in[j], &out1[j]);
            }
        }
    }
}

extern "C" void kernel_launch(void* const* d_in, const int* in_sizes, int n_in,
                              void* d_out, int out_size, void* d_ws, size_t ws_size,
                              hipStream_t stream) {
    const float* features   = (const float*)d_in[0];  // (1024, 256) f32
    const int*   pid_labels = (const int*)d_in[1];    // (1024,) int32
    const float* queue_in   = (const float*)d_in[2];  // (100000, 256) f32
    const float* qlabel_in  = (const float*)d_in[3];  // (100000,) f32
    const int n = in_sizes[1];

    float* out0 = (float*)d_out;                      // queue output
    float* out1 = out0 + (size_t)QSIZE * 256;         // qlabel output

    fused_kernel<<<NB_MAIN + NB_LAB, 256, 0, stream>>>(
        (const fvec4*)features, (const fvec4*)queue_in, qlabel_in,
        pid_labels, n, (fvec4*)out0, out1);
}